// Round 1
// baseline (8825.603 us; speedup 1.0000x reference)
//
#include <hip/hip_runtime.h>
#include <hip/hip_bf16.h>
#include <math.h>

// Problem constants (fixed by the reference)
constexpr int Bc = 128, Tc = 16, Lc = 196, Ec = 512, Hc = 1024, Vc = 32000;

__device__ __forceinline__ float sigmoidf_(float x) { return 1.0f / (1.0f + expf(-x)); }

// ---------------------------------------------------------------------------
// Generic tiled f32 GEMM: C[M,N] = A[M,K] @ B[K,N] (+ bias[N]) (+= C if acc)
// 64x64 tile, BK=16, 256 threads, 4x4 micro-tile per thread.
// Requires: M%64==0, N%64==0, K%16==0 (all shapes here satisfy this).
// grid = (M/64, N/64)
// ---------------------------------------------------------------------------
__global__ __launch_bounds__(256)
void gemm_f32(const float* __restrict__ A, int lda,
              const float* __restrict__ Bm, int ldb,
              float* __restrict__ C, int ldc,
              const float* __restrict__ bias,
              int K, int accumulate)
{
    __shared__ __align__(16) float As[16][68];   // [k][m], pad->row stride 272B (16B aligned)
    __shared__ __align__(16) float Bs[16][68];   // [k][n]
    const int t  = threadIdx.x;
    const int tx = t & 15;      // n direction
    const int ty = t >> 4;      // m direction
    const size_t m0 = (size_t)blockIdx.x * 64;
    const size_t n0 = (size_t)blockIdx.y * 64;

    const int arow = t >> 2;          // 0..63
    const int acol = (t & 3) << 2;    // 0,4,8,12
    const int brow = t >> 4;          // 0..15
    const int bcol = (t & 15) << 2;   // 0..60

    const float* Aptr = A + (m0 + arow) * (size_t)lda + acol;
    const float* Bptr = Bm + (size_t)brow * ldb + n0 + bcol;

    float acc[4][4] = {};

    for (int k0 = 0; k0 < K; k0 += 16) {
        float4 av = *reinterpret_cast<const float4*>(Aptr + k0);
        float4 bv = *reinterpret_cast<const float4*>(Bptr + (size_t)k0 * ldb);
        As[acol + 0][arow] = av.x;
        As[acol + 1][arow] = av.y;
        As[acol + 2][arow] = av.z;
        As[acol + 3][arow] = av.w;
        *reinterpret_cast<float4*>(&Bs[brow][bcol]) = bv;
        __syncthreads();
#pragma unroll
        for (int k = 0; k < 16; ++k) {
            float4 a4 = *reinterpret_cast<const float4*>(&As[k][ty << 2]);
            float4 b4 = *reinterpret_cast<const float4*>(&Bs[k][tx << 2]);
            float aa[4] = {a4.x, a4.y, a4.z, a4.w};
            float bb[4] = {b4.x, b4.y, b4.z, b4.w};
#pragma unroll
            for (int i = 0; i < 4; ++i)
#pragma unroll
                for (int j = 0; j < 4; ++j)
                    acc[i][j] = fmaf(aa[i], bb[j], acc[i][j]);
        }
        __syncthreads();
    }

    float4 bv4 = {0.f, 0.f, 0.f, 0.f};
    if (bias) bv4 = *reinterpret_cast<const float4*>(&bias[n0 + (tx << 2)]);
#pragma unroll
    for (int i = 0; i < 4; ++i) {
        size_t off = (m0 + (size_t)(ty << 2) + i) * (size_t)ldc + n0 + (tx << 2);
        float4 o;
        o.x = acc[i][0] + bv4.x;
        o.y = acc[i][1] + bv4.y;
        o.z = acc[i][2] + bv4.z;
        o.w = acc[i][3] + bv4.w;
        if (accumulate) {
            float4 prev = *reinterpret_cast<const float4*>(&C[off]);
            o.x += prev.x; o.y += prev.y; o.z += prev.z; o.w += prev.w;
        }
        *reinterpret_cast<float4*>(&C[off]) = o;
    }
}

// mean over L: mean_a[b,e] = (1/L) * sum_l feats[b,l,e]   grid=(B, E/256)
__global__ __launch_bounds__(256)
void mean_kernel(const float* __restrict__ feats, float* __restrict__ mean_a)
{
    int b = blockIdx.x;
    int e = blockIdx.y * 256 + threadIdx.x;
    const float* f = feats + ((size_t)b * Lc) * Ec + e;
    float s = 0.f;
    for (int l = 0; l < Lc; ++l) s += f[(size_t)l * Ec];
    mean_a[b * Ec + e] = s * (1.0f / Lc);
}

// e[b,l] = sum_h relu(q[b,h] + keys[b,l,h]) * V_a[h] + b_va
// 4 waves/block, one (b,l) pair per wave. grid = B*L/4
__global__ __launch_bounds__(256)
void att_scores(const float* __restrict__ q, const float* __restrict__ keys,
                const float* __restrict__ V_a, const float* __restrict__ b_va,
                float* __restrict__ e)
{
    int pair = blockIdx.x * 4 + (threadIdx.x >> 6);
    int lane = threadIdx.x & 63;
    int b = pair / Lc;
    const float* qp = q + (size_t)b * Hc;
    const float* kp = keys + (size_t)pair * Hc;
    float s = 0.f;
    for (int h = lane; h < Hc; h += 64)
        s = fmaf(fmaxf(qp[h] + kp[h], 0.f), V_a[h], s);
#pragma unroll
    for (int off = 32; off > 0; off >>= 1) s += __shfl_down(s, off);
    if (lane == 0) e[pair] = s + b_va[0];
}

// softmax over L (in place on e[b,:]), grid = B, 256 threads (L=196)
__global__ __launch_bounds__(256)
void softmax_L(float* __restrict__ e)
{
    int b = blockIdx.x;
    float* p = e + b * Lc;
    __shared__ float red[256];
    int tid = threadIdx.x;
    float m = -1e30f;
    if (tid < Lc) m = p[tid];
    red[tid] = m; __syncthreads();
    for (int s = 128; s > 0; s >>= 1) { if (tid < s) red[tid] = fmaxf(red[tid], red[tid + s]); __syncthreads(); }
    m = red[0]; __syncthreads();
    float ex = 0.f;
    if (tid < Lc) ex = expf(p[tid] - m);
    red[tid] = ex; __syncthreads();
    for (int s = 128; s > 0; s >>= 1) { if (tid < s) red[tid] += red[tid + s]; __syncthreads(); }
    if (tid < Lc) p[tid] = ex / red[0];
}

// z[b,e] = sum_l alpha[b,l] * feats[b,l,e]   grid=(B, E/256)
__global__ __launch_bounds__(256)
void z_kernel(const float* __restrict__ alpha, const float* __restrict__ feats,
              float* __restrict__ z)
{
    int b = blockIdx.x;
    int e = blockIdx.y * 256 + threadIdx.x;
    const float* f = feats + ((size_t)b * Lc) * Ec + e;
    const float* a = alpha + b * Lc;
    float s = 0.f;
    for (int l = 0; l < Lc; ++l) s = fmaf(a[l], f[(size_t)l * Ec], s);
    z[b * Ec + e] = s;
}

// ctx[b, 0:E]  = z * sigmoid(sb);  ctx[b, E:2E] = emb[caption[b,t]]
// grid = (B, 2E/256)
__global__ __launch_bounds__(256)
void ctx_build(const float* __restrict__ z, const float* __restrict__ sb,
               const int* __restrict__ caption, const float* __restrict__ emb,
               float* __restrict__ ctx, int t)
{
    int b = blockIdx.x;
    int j = blockIdx.y * 256 + threadIdx.x;
    float v;
    if (j < Ec) {
        v = z[b * Ec + j] * sigmoidf_(sb[b * Ec + j]);
    } else {
        int tok = caption[b * Tc + t];
        v = emb[(size_t)tok * Ec + (j - Ec)];
    }
    ctx[b * (2 * Ec) + j] = v;
}

// LSTM elementwise: gates[b, 0:4H] (i,f,g,o), update c,h in place. grid=B*H/256
__global__ __launch_bounds__(256)
void lstm_elem(const float* __restrict__ gates, float* __restrict__ c, float* __restrict__ h)
{
    int idx = blockIdx.x * 256 + threadIdx.x;
    int b = idx >> 10;          // / H (H=1024)
    int j = idx & (Hc - 1);
    const float* g = gates + (size_t)b * 4 * Hc;
    float gi = g[j], gf = g[Hc + j], gg = g[2 * Hc + j], go = g[3 * Hc + j];
    float cn = sigmoidf_(gf) * c[idx] + sigmoidf_(gi) * tanhf(gg);
    c[idx] = cn;
    h[idx] = sigmoidf_(go) * tanhf(cn);
}

// softmax over V in place on out[b,t,:]. grid = B, 256 threads
__global__ __launch_bounds__(256)
void softmax_V(float* __restrict__ out, int t)
{
    int b = blockIdx.x;
    float* p = out + ((size_t)b * Tc + t) * (size_t)Vc;
    __shared__ float red[256];
    int tid = threadIdx.x;
    float m = -1e30f;
    for (int v = tid; v < Vc; v += 256) m = fmaxf(m, p[v]);
    red[tid] = m; __syncthreads();
    for (int s = 128; s > 0; s >>= 1) { if (tid < s) red[tid] = fmaxf(red[tid], red[tid + s]); __syncthreads(); }
    m = red[0]; __syncthreads();
    float sum = 0.f;
    for (int v = tid; v < Vc; v += 256) { float ex = expf(p[v] - m); p[v] = ex; sum += ex; }
    red[tid] = sum; __syncthreads();
    for (int s = 128; s > 0; s >>= 1) { if (tid < s) red[tid] += red[tid + s]; __syncthreads(); }
    float inv = 1.0f / red[0];
    __syncthreads();
    for (int v = tid; v < Vc; v += 256) p[v] *= inv;
}

extern "C" void kernel_launch(void* const* d_in, const int* in_sizes, int n_in,
                              void* d_out, int out_size, void* d_ws, size_t ws_size,
                              hipStream_t stream)
{
    const int*   caption  = (const int*)  d_in[0];
    const float* feats    = (const float*)d_in[1];
    const float* emb      = (const float*)d_in[2];
    const float* W_init_h = (const float*)d_in[3];
    const float* b_init_h = (const float*)d_in[4];
    const float* W_init_c = (const float*)d_in[5];
    const float* b_init_c = (const float*)d_in[6];
    const float* W_a      = (const float*)d_in[7];
    const float* b_a      = (const float*)d_in[8];
    const float* U_a      = (const float*)d_in[9];
    const float* b_ua     = (const float*)d_in[10];
    const float* V_a      = (const float*)d_in[11];
    const float* b_va     = (const float*)d_in[12];
    const float* W_beta   = (const float*)d_in[13];
    const float* b_beta   = (const float*)d_in[14];
    const float* W_lstm   = (const float*)d_in[15];
    const float* U_lstm   = (const float*)d_in[16];
    const float* b_lstm   = (const float*)d_in[17];
    const float* W_out    = (const float*)d_in[18];
    const float* b_out    = (const float*)d_in[19];
    float* out = (float*)d_out;

    // workspace layout (floats)
    float* ws = (float*)d_ws;
    size_t off = 0;
    float* keys  = ws + off; off += (size_t)Bc * Lc * Hc;   // 25,690,112
    float* h     = ws + off; off += (size_t)Bc * Hc;
    float* c     = ws + off; off += (size_t)Bc * Hc;
    float* q     = ws + off; off += (size_t)Bc * Hc;
    float* e     = ws + off; off += (size_t)Bc * Lc;
    float* sb    = ws + off; off += (size_t)Bc * Ec;
    float* z     = ws + off; off += (size_t)Bc * Ec;
    float* ctx   = ws + off; off += (size_t)Bc * 2 * Ec;
    float* gates = ws + off; off += (size_t)Bc * 4 * Hc;
    float* mean_a= ws + off; off += (size_t)Bc * Ec;
    if (ws_size < off * sizeof(float)) return;  // workspace too small -> fail loudly

    dim3 blk(256);

    // ---- setup (once) ----
    mean_kernel<<<dim3(Bc, Ec / 256), blk, 0, stream>>>(feats, mean_a);
    // h0 = mean_a @ W_init_h + b_init_h ; c0 likewise
    gemm_f32<<<dim3(Bc / 64, Hc / 64), blk, 0, stream>>>(mean_a, Ec, W_init_h, Hc, h, Hc, b_init_h, Ec, 0);
    gemm_f32<<<dim3(Bc / 64, Hc / 64), blk, 0, stream>>>(mean_a, Ec, W_init_c, Hc, c, Hc, b_init_c, Ec, 0);
    // keys = feats(as [B*L, E]) @ U_a + b_ua   -> [B*L, H]
    gemm_f32<<<dim3((Bc * Lc) / 64, Hc / 64), blk, 0, stream>>>(feats, Ec, U_a, Hc, keys, Hc, b_ua, Ec, 0);

    // ---- time steps ----
    for (int t = 0; t < Tc; ++t) {
        // q = h @ W_a + b_a
        gemm_f32<<<dim3(Bc / 64, Hc / 64), blk, 0, stream>>>(h, Hc, W_a, Hc, q, Hc, b_a, Hc, 0);
        // attention scores + softmax + context
        att_scores<<<dim3((Bc * Lc) / 4), blk, 0, stream>>>(q, keys, V_a, b_va, e);
        softmax_L<<<dim3(Bc), blk, 0, stream>>>(e);
        z_kernel<<<dim3(Bc, Ec / 256), blk, 0, stream>>>(e, feats, z);
        // sb = h @ W_beta + b_beta
        gemm_f32<<<dim3(Bc / 64, Ec / 64), blk, 0, stream>>>(h, Hc, W_beta, Ec, sb, Ec, b_beta, Hc, 0);
        // ctx = [z * sigmoid(sb), emb[caption[:,t]]]
        ctx_build<<<dim3(Bc, (2 * Ec) / 256), blk, 0, stream>>>(z, sb, caption, emb, ctx, t);
        // gates = ctx @ W_lstm + b_lstm ; gates += h @ U_lstm
        gemm_f32<<<dim3(Bc / 64, (4 * Hc) / 64), blk, 0, stream>>>(ctx, 2 * Ec, W_lstm, 4 * Hc, gates, 4 * Hc, b_lstm, 2 * Ec, 0);
        gemm_f32<<<dim3(Bc / 64, (4 * Hc) / 64), blk, 0, stream>>>(h, Hc, U_lstm, 4 * Hc, gates, 4 * Hc, nullptr, Hc, 1);
        // c,h update
        lstm_elem<<<dim3((Bc * Hc) / 256), blk, 0, stream>>>(gates, c, h);
        // logits -> d_out slice, then softmax in place
        gemm_f32<<<dim3(Bc / 64, Vc / 64), blk, 0, stream>>>(h, Hc, W_out, Vc, out + (size_t)t * Vc, Tc * Vc, b_out, Hc, 0);
        softmax_V<<<dim3(Bc), blk, 0, stream>>>(out, t);
    }
}

// Round 2
// 6387.269 us; speedup vs baseline: 1.3817x; 1.3817x over previous
//
#include <hip/hip_runtime.h>
#include <hip/hip_bf16.h>
#include <math.h>

// Problem constants (fixed by the reference)
constexpr int Bc = 128, Tc = 16, Lc = 196, Ec = 512, Hc = 1024, Vc = 32000;

typedef float f32x4_t __attribute__((ext_vector_type(4)));
typedef short s16x8_t __attribute__((ext_vector_type(8)));

__device__ __forceinline__ float sigmoidf_(float x) { return 1.0f / (1.0f + expf(-x)); }

__device__ __forceinline__ unsigned short bf16rn(float x) {
    union { float f; unsigned u; } v; v.f = x;
    unsigned r = v.u + 0x7fffu + ((v.u >> 16) & 1u);
    return (unsigned short)(r >> 16);
}
__device__ __forceinline__ float bf16tof(unsigned short h) {
    union { unsigned u; float f; } v; v.u = ((unsigned)h) << 16; return v.f;
}

// ---------------------------------------------------------------------------
// Weight prep: src [K][N] f32 (row-major)  ->  dhi/dlo [N][ldd] bf16 bits
// (transposed + split into hi/lo bf16).  grid = (K/32, N/32), 256 threads.
// ---------------------------------------------------------------------------
__global__ __launch_bounds__(256)
void transpose_split(const float* __restrict__ src, int N,
                     unsigned short* __restrict__ dhi, unsigned short* __restrict__ dlo,
                     int ldd)
{
    __shared__ float tile[32][33];
    const int k0 = blockIdx.x * 32, n0 = blockIdx.y * 32;
    const int tx = threadIdx.x & 31, ty = threadIdx.x >> 5;  // ty 0..7
#pragma unroll
    for (int i = 0; i < 4; ++i)
        tile[ty + i * 8][tx] = src[(size_t)(k0 + ty + i * 8) * N + n0 + tx];
    __syncthreads();
#pragma unroll
    for (int i = 0; i < 4; ++i) {
        int nl = ty + i * 8;
        float v = tile[tx][nl];
        unsigned short hi = bf16rn(v);
        unsigned short lo = bf16rn(v - bf16tof(hi));
        size_t off = (size_t)(n0 + nl) * ldd + k0 + tx;
        dhi[off] = hi;
        dlo[off] = lo;
    }
}

// ---------------------------------------------------------------------------
// Split-bf16 MFMA GEMM: C[M,N] = A[M,K](f32) @ B[K,N] (+bias), where B is
// given pre-transposed/split: Bhi/Blo [N][K] bf16 bits.
// acc += Ahi*Bhi + Ahi*Blo + Alo*Bhi   (lo*lo dropped, ~2^-18 relative)
// Block: 256 thr = 4 waves (2x2), tile 128x128, BK=32, 16x16x32 MFMA.
// Requires M%128==0, N%128==0, K%32==0. grid = (M/128, N/128).
// ---------------------------------------------------------------------------
__global__ __launch_bounds__(256)
void gemm_mfma_split(const float* __restrict__ A, int lda,
                     const unsigned short* __restrict__ Bhi,
                     const unsigned short* __restrict__ Blo,
                     float* __restrict__ C, long ldc,
                     const float* __restrict__ bias, int K)
{
    __shared__ unsigned short As_hi[128][32], As_lo[128][32];
    __shared__ unsigned short Bs_hi[128][32], Bs_lo[128][32];

    const int t = threadIdx.x;
    const int wave = t >> 6, lane = t & 63;
    const int wr = wave >> 1, wc = wave & 1;   // wave 2x2 within 128x128 tile
    const int lm = lane & 15, qd = lane >> 4;  // fragment coords
    const size_t m0 = (size_t)blockIdx.x * 128;
    const size_t n0 = (size_t)blockIdx.y * 128;

    // staging assignment: thread -> (row = t>>1, k-half = (t&1)*16)
    const int srow = t >> 1;
    const int skh  = (t & 1) * 16;

    const float* Ap = A + (m0 + srow) * (size_t)lda + skh;
    const unsigned short* Bhp = Bhi + (n0 + srow) * (size_t)K + skh;
    const unsigned short* Blp = Blo + (n0 + srow) * (size_t)K + skh;

    f32x4_t acc[4][4];
#pragma unroll
    for (int i = 0; i < 4; ++i)
#pragma unroll
        for (int j = 0; j < 4; ++j)
            acc[i][j] = (f32x4_t){0.f, 0.f, 0.f, 0.f};

    for (int k0 = 0; k0 < K; k0 += 32) {
        // ---- stage A (f32 -> hi/lo bf16) ----
        float av[16];
        *(float4*)&av[0]  = *(const float4*)(Ap + k0);
        *(float4*)&av[4]  = *(const float4*)(Ap + k0 + 4);
        *(float4*)&av[8]  = *(const float4*)(Ap + k0 + 8);
        *(float4*)&av[12] = *(const float4*)(Ap + k0 + 12);
        s16x8_t h0, h1, l0, l1;
#pragma unroll
        for (int i = 0; i < 8; ++i) {
            unsigned short hi = bf16rn(av[i]);
            h0[i] = (short)hi;
            l0[i] = (short)bf16rn(av[i] - bf16tof(hi));
        }
#pragma unroll
        for (int i = 0; i < 8; ++i) {
            unsigned short hi = bf16rn(av[8 + i]);
            h1[i] = (short)hi;
            l1[i] = (short)bf16rn(av[8 + i] - bf16tof(hi));
        }
        *(s16x8_t*)&As_hi[srow][skh]     = h0;
        *(s16x8_t*)&As_hi[srow][skh + 8] = h1;
        *(s16x8_t*)&As_lo[srow][skh]     = l0;
        *(s16x8_t*)&As_lo[srow][skh + 8] = l1;
        // ---- stage B (already bf16 bits, transposed) ----
        *(s16x8_t*)&Bs_hi[srow][skh]     = *(const s16x8_t*)(Bhp + k0);
        *(s16x8_t*)&Bs_hi[srow][skh + 8] = *(const s16x8_t*)(Bhp + k0 + 8);
        *(s16x8_t*)&Bs_lo[srow][skh]     = *(const s16x8_t*)(Blp + k0);
        *(s16x8_t*)&Bs_lo[srow][skh + 8] = *(const s16x8_t*)(Blp + k0 + 8);
        __syncthreads();

        s16x8_t ah[4], al[4], bh[4], bl[4];
#pragma unroll
        for (int mt = 0; mt < 4; ++mt) {
            ah[mt] = *(const s16x8_t*)&As_hi[wr * 64 + mt * 16 + lm][qd * 8];
            al[mt] = *(const s16x8_t*)&As_lo[wr * 64 + mt * 16 + lm][qd * 8];
        }
#pragma unroll
        for (int nt = 0; nt < 4; ++nt) {
            bh[nt] = *(const s16x8_t*)&Bs_hi[wc * 64 + nt * 16 + lm][qd * 8];
            bl[nt] = *(const s16x8_t*)&Bs_lo[wc * 64 + nt * 16 + lm][qd * 8];
        }
#pragma unroll
        for (int mt = 0; mt < 4; ++mt)
#pragma unroll
            for (int nt = 0; nt < 4; ++nt) {
                acc[mt][nt] = __builtin_amdgcn_mfma_f32_16x16x32_bf16(ah[mt], bh[nt], acc[mt][nt], 0, 0, 0);
                acc[mt][nt] = __builtin_amdgcn_mfma_f32_16x16x32_bf16(ah[mt], bl[nt], acc[mt][nt], 0, 0, 0);
                acc[mt][nt] = __builtin_amdgcn_mfma_f32_16x16x32_bf16(al[mt], bh[nt], acc[mt][nt], 0, 0, 0);
            }
        __syncthreads();
    }

    // epilogue: C/D layout col=lane&15, row=qd*4+reg
#pragma unroll
    for (int nt = 0; nt < 4; ++nt) {
        size_t n = n0 + wc * 64 + nt * 16 + lm;
        float bs = bias ? bias[n] : 0.f;
#pragma unroll
        for (int mt = 0; mt < 4; ++mt) {
#pragma unroll
            for (int r = 0; r < 4; ++r) {
                size_t m = m0 + wr * 64 + mt * 16 + qd * 4 + r;
                C[(size_t)m * ldc + n] = acc[mt][nt][r] + bs;
            }
        }
    }
}

// concat two f32 vectors
__global__ __launch_bounds__(256)
void concat2(const float* __restrict__ a, int na, const float* __restrict__ b, int nb,
             float* __restrict__ out)
{
    int i = blockIdx.x * 256 + threadIdx.x;
    if (i < na) out[i] = a[i];
    else if (i < na + nb) out[i] = b[i - na];
}

// mean over L: mean_a[b,e] = (1/L) * sum_l feats[b,l,e]   grid=(B, E/256)
__global__ __launch_bounds__(256)
void mean_kernel(const float* __restrict__ feats, float* __restrict__ mean_a)
{
    int b = blockIdx.x;
    int e = blockIdx.y * 256 + threadIdx.x;
    const float* f = feats + ((size_t)b * Lc) * Ec + e;
    float s = 0.f;
    for (int l = 0; l < Lc; ++l) s += f[(size_t)l * Ec];
    mean_a[b * Ec + e] = s * (1.0f / Lc);
}

// e[b,l] = sum_h relu(q[b,h] + keys[b,l,h]) * V_a[h] + b_va ; ldq = q row stride
__global__ __launch_bounds__(256)
void att_scores(const float* __restrict__ q, int ldq, const float* __restrict__ keys,
                const float* __restrict__ V_a, const float* __restrict__ b_va,
                float* __restrict__ e)
{
    int pair = blockIdx.x * 4 + (threadIdx.x >> 6);
    int lane = threadIdx.x & 63;
    int b = pair / Lc;
    const float* qp = q + (size_t)b * ldq;
    const float* kp = keys + (size_t)pair * Hc;
    float s = 0.f;
    for (int h = lane; h < Hc; h += 64)
        s = fmaf(fmaxf(qp[h] + kp[h], 0.f), V_a[h], s);
#pragma unroll
    for (int off = 32; off > 0; off >>= 1) s += __shfl_down(s, off);
    if (lane == 0) e[pair] = s + b_va[0];
}

// softmax over L (in place on e[b,:]), grid = B
__global__ __launch_bounds__(256)
void softmax_L(float* __restrict__ e)
{
    int b = blockIdx.x;
    float* p = e + b * Lc;
    __shared__ float red[256];
    int tid = threadIdx.x;
    float m = -1e30f;
    if (tid < Lc) m = p[tid];
    red[tid] = m; __syncthreads();
    for (int s = 128; s > 0; s >>= 1) { if (tid < s) red[tid] = fmaxf(red[tid], red[tid + s]); __syncthreads(); }
    m = red[0]; __syncthreads();
    float ex = 0.f;
    if (tid < Lc) ex = expf(p[tid] - m);
    red[tid] = ex; __syncthreads();
    for (int s = 128; s > 0; s >>= 1) { if (tid < s) red[tid] += red[tid + s]; __syncthreads(); }
    if (tid < Lc) p[tid] = ex / red[0];
}

// z[b,e] = sum_l alpha[b,l] * feats[b,l,e]   grid=(B, E/256)
__global__ __launch_bounds__(256)
void z_kernel(const float* __restrict__ alpha, const float* __restrict__ feats,
              float* __restrict__ z)
{
    int b = blockIdx.x;
    int e = blockIdx.y * 256 + threadIdx.x;
    const float* f = feats + ((size_t)b * Lc) * Ec + e;
    const float* a = alpha + b * Lc;
    float s = 0.f;
    for (int l = 0; l < Lc; ++l) s = fmaf(a[l], f[(size_t)l * Ec], s);
    z[b * Ec + e] = s;
}

// fast path: xcat[b] = [z*sigmoid(sb) | emb[tok] | h]  (2048 wide), grid=(B,8)
__global__ __launch_bounds__(256)
void xcat_build(const float* __restrict__ z, const float* __restrict__ qsb,
                const int* __restrict__ caption, const float* __restrict__ emb,
                const float* __restrict__ hc, float* __restrict__ xcat, int t)
{
    int b = blockIdx.x;
    int j = blockIdx.y * 256 + threadIdx.x;
    float v;
    if (j < Ec) {
        float sb = qsb[(size_t)b * 1536 + 1024 + j];
        v = z[b * Ec + j] * sigmoidf_(sb);
    } else if (j < 2 * Ec) {
        int tok = caption[b * Tc + t];
        v = emb[(size_t)tok * Ec + (j - Ec)];
    } else {
        v = hc[(size_t)b * 2048 + (j - 2 * Ec)];
    }
    xcat[(size_t)b * 2048 + j] = v;
}

// legacy ctx build: ctx[b] = [z*sigmoid(sb) | emb[tok]] (1024 wide), grid=(B,4)
__global__ __launch_bounds__(256)
void ctx_build(const float* __restrict__ z, const float* __restrict__ sb,
               const int* __restrict__ caption, const float* __restrict__ emb,
               float* __restrict__ ctx, int t)
{
    int b = blockIdx.x;
    int j = blockIdx.y * 256 + threadIdx.x;
    float v;
    if (j < Ec) {
        v = z[b * Ec + j] * sigmoidf_(sb[b * Ec + j]);
    } else {
        int tok = caption[b * Tc + t];
        v = emb[(size_t)tok * Ec + (j - Ec)];
    }
    ctx[b * (2 * Ec) + j] = v;
}

// LSTM elementwise; h at hbase[b*ld + j], c at cbase[b*ld + j]. grid=B*H/256
__global__ __launch_bounds__(256)
void lstm_elem(const float* __restrict__ gates, float* __restrict__ hbase,
               float* __restrict__ cbase, int ld)
{
    int idx = blockIdx.x * 256 + threadIdx.x;
    int b = idx >> 10;
    int j = idx & (Hc - 1);
    const float* g = gates + (size_t)b * 4 * Hc;
    float gi = g[j], gf = g[Hc + j], gg = g[2 * Hc + j], go = g[3 * Hc + j];
    float* cp = cbase + (size_t)b * ld + j;
    float* hp = hbase + (size_t)b * ld + j;
    float cn = sigmoidf_(gf) * (*cp) + sigmoidf_(gi) * tanhf(gg);
    *cp = cn;
    *hp = sigmoidf_(go) * tanhf(cn);
}

// softmax over V in place on out[b,t,:]. grid = B
__global__ __launch_bounds__(256)
void softmax_V(float* __restrict__ out, int t)
{
    int b = blockIdx.x;
    float* p = out + ((size_t)b * Tc + t) * (size_t)Vc;
    __shared__ float red[256];
    int tid = threadIdx.x;
    float m = -1e30f;
    for (int v = tid; v < Vc; v += 256) m = fmaxf(m, p[v]);
    red[tid] = m; __syncthreads();
    for (int s = 128; s > 0; s >>= 1) { if (tid < s) red[tid] = fmaxf(red[tid], red[tid + s]); __syncthreads(); }
    m = red[0]; __syncthreads();
    float sum = 0.f;
    for (int v = tid; v < Vc; v += 256) { float ex = expf(p[v] - m); p[v] = ex; sum += ex; }
    red[tid] = sum; __syncthreads();
    for (int s = 128; s > 0; s >>= 1) { if (tid < s) red[tid] += red[tid + s]; __syncthreads(); }
    float inv = 1.0f / red[0];
    __syncthreads();
    for (int v = tid; v < Vc; v += 256) p[v] *= inv;
}

// ---------------------------------------------------------------------------
// Legacy f32 tiled GEMM (fallback path if workspace too small)
// ---------------------------------------------------------------------------
__global__ __launch_bounds__(256)
void gemm_f32(const float* __restrict__ A, int lda,
              const float* __restrict__ Bm, int ldb,
              float* __restrict__ C, int ldc,
              const float* __restrict__ bias,
              int K, int accumulate)
{
    __shared__ __align__(16) float As[16][68];
    __shared__ __align__(16) float Bs[16][68];
    const int t  = threadIdx.x;
    const int tx = t & 15;
    const int ty = t >> 4;
    const size_t m0 = (size_t)blockIdx.x * 64;
    const size_t n0 = (size_t)blockIdx.y * 64;
    const int arow = t >> 2;
    const int acol = (t & 3) << 2;
    const int brow = t >> 4;
    const int bcol = (t & 15) << 2;
    const float* Aptr = A + (m0 + arow) * (size_t)lda + acol;
    const float* Bptr = Bm + (size_t)brow * ldb + n0 + bcol;
    float acc[4][4] = {};
    for (int k0 = 0; k0 < K; k0 += 16) {
        float4 av = *reinterpret_cast<const float4*>(Aptr + k0);
        float4 bv = *reinterpret_cast<const float4*>(Bptr + (size_t)k0 * ldb);
        As[acol + 0][arow] = av.x;
        As[acol + 1][arow] = av.y;
        As[acol + 2][arow] = av.z;
        As[acol + 3][arow] = av.w;
        *reinterpret_cast<float4*>(&Bs[brow][bcol]) = bv;
        __syncthreads();
#pragma unroll
        for (int k = 0; k < 16; ++k) {
            float4 a4 = *reinterpret_cast<const float4*>(&As[k][ty << 2]);
            float4 b4 = *reinterpret_cast<const float4*>(&Bs[k][tx << 2]);
            float aa[4] = {a4.x, a4.y, a4.z, a4.w};
            float bb[4] = {b4.x, b4.y, b4.z, b4.w};
#pragma unroll
            for (int i = 0; i < 4; ++i)
#pragma unroll
                for (int j = 0; j < 4; ++j)
                    acc[i][j] = fmaf(aa[i], bb[j], acc[i][j]);
        }
        __syncthreads();
    }
    float4 bv4 = {0.f, 0.f, 0.f, 0.f};
    if (bias) bv4 = *reinterpret_cast<const float4*>(&bias[n0 + (tx << 2)]);
#pragma unroll
    for (int i = 0; i < 4; ++i) {
        size_t off = (m0 + (size_t)(ty << 2) + i) * (size_t)ldc + n0 + (tx << 2);
        float4 o;
        o.x = acc[i][0] + bv4.x;
        o.y = acc[i][1] + bv4.y;
        o.z = acc[i][2] + bv4.z;
        o.w = acc[i][3] + bv4.w;
        if (accumulate) {
            float4 prev = *reinterpret_cast<const float4*>(&C[off]);
            o.x += prev.x; o.y += prev.y; o.z += prev.z; o.w += prev.w;
        }
        *reinterpret_cast<float4*>(&C[off]) = o;
    }
}

extern "C" void kernel_launch(void* const* d_in, const int* in_sizes, int n_in,
                              void* d_out, int out_size, void* d_ws, size_t ws_size,
                              hipStream_t stream)
{
    const int*   caption  = (const int*)  d_in[0];
    const float* feats    = (const float*)d_in[1];
    const float* emb      = (const float*)d_in[2];
    const float* W_init_h = (const float*)d_in[3];
    const float* b_init_h = (const float*)d_in[4];
    const float* W_init_c = (const float*)d_in[5];
    const float* b_init_c = (const float*)d_in[6];
    const float* W_a      = (const float*)d_in[7];
    const float* b_a      = (const float*)d_in[8];
    const float* U_a      = (const float*)d_in[9];
    const float* b_ua     = (const float*)d_in[10];
    const float* V_a      = (const float*)d_in[11];
    const float* b_va     = (const float*)d_in[12];
    const float* W_beta   = (const float*)d_in[13];
    const float* b_beta   = (const float*)d_in[14];
    const float* W_lstm   = (const float*)d_in[15];
    const float* U_lstm   = (const float*)d_in[16];
    const float* b_lstm   = (const float*)d_in[17];
    const float* W_out    = (const float*)d_in[18];
    const float* b_out    = (const float*)d_in[19];
    float* out = (float*)d_out;

    dim3 blk(256);

    // ---------------- fast-path workspace layout (bytes) ----------------
    char* base = (char*)d_ws;
    size_t off = 0;
    auto alloc = [&](size_t bytes) { char* p = base + off; off = (off + bytes + 15) & ~(size_t)15; return p; };

    float* keys   = (float*)alloc((size_t)Bc * Lc * Hc * 4);
    float* hc     = (float*)alloc((size_t)Bc * 2048 * 4);      // h | c interleaved per row
    float* qsb    = (float*)alloc((size_t)Bc * 1536 * 4);      // q | sb
    float* e      = (float*)alloc((size_t)Bc * Lc * 4);
    float* z      = (float*)alloc((size_t)Bc * Ec * 4);
    float* xcat   = (float*)alloc((size_t)Bc * 2048 * 4);      // z*sig | emb | h
    float* gates  = (float*)alloc((size_t)Bc * 4 * Hc * 4);
    float* mean_a = (float*)alloc((size_t)Bc * Ec * 4);
    float* bcat_i = (float*)alloc(2048 * 4);
    float* bcat_q = (float*)alloc(1536 * 4);
    unsigned short* Wout_hi  = (unsigned short*)alloc((size_t)Vc * Hc * 2);
    unsigned short* Wout_lo  = (unsigned short*)alloc((size_t)Vc * Hc * 2);
    unsigned short* Wg_hi    = (unsigned short*)alloc((size_t)4096 * 2048 * 2);
    unsigned short* Wg_lo    = (unsigned short*)alloc((size_t)4096 * 2048 * 2);
    unsigned short* Wqsb_hi  = (unsigned short*)alloc((size_t)1536 * 1024 * 2);
    unsigned short* Wqsb_lo  = (unsigned short*)alloc((size_t)1536 * 1024 * 2);
    unsigned short* Ua_hi    = (unsigned short*)alloc((size_t)1024 * 512 * 2);
    unsigned short* Ua_lo    = (unsigned short*)alloc((size_t)1024 * 512 * 2);
    unsigned short* Wini_hi  = (unsigned short*)alloc((size_t)2048 * 512 * 2);
    unsigned short* Wini_lo  = (unsigned short*)alloc((size_t)2048 * 512 * 2);
    const size_t need_fast = off;

    if (ws_size >= need_fast) {
        // ================= fast path: split-bf16 MFMA =================
        // ---- weight prep (per call; same work every call) ----
        transpose_split<<<dim3(16, 32), blk, 0, stream>>>(U_a, 1024, Ua_hi, Ua_lo, 512);
        transpose_split<<<dim3(16, 32), blk, 0, stream>>>(W_init_h, 1024, Wini_hi, Wini_lo, 512);
        transpose_split<<<dim3(16, 32), blk, 0, stream>>>(W_init_c, 1024, Wini_hi + (size_t)1024 * 512, Wini_lo + (size_t)1024 * 512, 512);
        transpose_split<<<dim3(32, 32), blk, 0, stream>>>(W_a, 1024, Wqsb_hi, Wqsb_lo, 1024);
        transpose_split<<<dim3(32, 16), blk, 0, stream>>>(W_beta, 512, Wqsb_hi + (size_t)1024 * 1024, Wqsb_lo + (size_t)1024 * 1024, 1024);
        transpose_split<<<dim3(32, 128), blk, 0, stream>>>(W_lstm, 4096, Wg_hi, Wg_lo, 2048);
        transpose_split<<<dim3(32, 128), blk, 0, stream>>>(U_lstm, 4096, Wg_hi + 1024, Wg_lo + 1024, 2048);
        transpose_split<<<dim3(32, 1000), blk, 0, stream>>>(W_out, Vc, Wout_hi, Wout_lo, 1024);
        concat2<<<dim3(8), blk, 0, stream>>>(b_init_h, 1024, b_init_c, 1024, bcat_i);
        concat2<<<dim3(6), blk, 0, stream>>>(b_a, 1024, b_beta, 512, bcat_q);

        // ---- setup ----
        mean_kernel<<<dim3(Bc, 2), blk, 0, stream>>>(feats, mean_a);
        // hc = mean_a @ [W_init_h | W_init_c] + [b_init_h | b_init_c]
        gemm_mfma_split<<<dim3(1, 16), blk, 0, stream>>>(mean_a, Ec, Wini_hi, Wini_lo, hc, 2048, bcat_i, 512);
        // keys = feats @ U_a + b_ua
        gemm_mfma_split<<<dim3((Bc * Lc) / 128, 8), blk, 0, stream>>>(feats, Ec, Ua_hi, Ua_lo, keys, Hc, b_ua, 512);

        // ---- time steps ----
        for (int t = 0; t < Tc; ++t) {
            // qsb = h @ [W_a | W_beta] + [b_a | b_beta]
            gemm_mfma_split<<<dim3(1, 12), blk, 0, stream>>>(hc, 2048, Wqsb_hi, Wqsb_lo, qsb, 1536, bcat_q, 1024);
            att_scores<<<dim3((Bc * Lc) / 4), blk, 0, stream>>>(qsb, 1536, keys, V_a, b_va, e);
            softmax_L<<<dim3(Bc), blk, 0, stream>>>(e);
            z_kernel<<<dim3(Bc, 2), blk, 0, stream>>>(e, feats, z);
            xcat_build<<<dim3(Bc, 8), blk, 0, stream>>>(z, qsb, caption, emb, hc, xcat, t);
            // gates = [ctx | h] @ [W_lstm ; U_lstm] + b_lstm
            gemm_mfma_split<<<dim3(1, 32), blk, 0, stream>>>(xcat, 2048, Wg_hi, Wg_lo, gates, 4096, b_lstm, 2048);
            lstm_elem<<<dim3((Bc * Hc) / 256), blk, 0, stream>>>(gates, hc, hc + 1024, 2048);
            // logits into d_out slice, softmax in place
            gemm_mfma_split<<<dim3(1, 250), blk, 0, stream>>>(hc, 2048, Wout_hi, Wout_lo, out + (size_t)t * Vc, (long)Tc * Vc, b_out, 1024);
            softmax_V<<<dim3(Bc), blk, 0, stream>>>(out, t);
        }
        return;
    }

    // ================= legacy f32 fallback =================
    float* ws = (float*)d_ws;
    size_t foff = 0;
    float* l_keys  = ws + foff; foff += (size_t)Bc * Lc * Hc;
    float* l_h     = ws + foff; foff += (size_t)Bc * Hc;
    float* l_c     = ws + foff; foff += (size_t)Bc * Hc;
    float* l_q     = ws + foff; foff += (size_t)Bc * Hc;
    float* l_e     = ws + foff; foff += (size_t)Bc * Lc;
    float* l_sb    = ws + foff; foff += (size_t)Bc * Ec;
    float* l_z     = ws + foff; foff += (size_t)Bc * Ec;
    float* l_ctx   = ws + foff; foff += (size_t)Bc * 2 * Ec;
    float* l_gates = ws + foff; foff += (size_t)Bc * 4 * Hc;
    float* l_mean  = ws + foff; foff += (size_t)Bc * Ec;
    if (ws_size < foff * sizeof(float)) return;

    mean_kernel<<<dim3(Bc, 2), blk, 0, stream>>>(feats, l_mean);
    gemm_f32<<<dim3(Bc / 64, Hc / 64), blk, 0, stream>>>(l_mean, Ec, W_init_h, Hc, l_h, Hc, b_init_h, Ec, 0);
    gemm_f32<<<dim3(Bc / 64, Hc / 64), blk, 0, stream>>>(l_mean, Ec, W_init_c, Hc, l_c, Hc, b_init_c, Ec, 0);
    gemm_f32<<<dim3((Bc * Lc) / 64, Hc / 64), blk, 0, stream>>>(feats, Ec, U_a, Hc, l_keys, Hc, b_ua, Ec, 0);
    for (int t = 0; t < Tc; ++t) {
        gemm_f32<<<dim3(Bc / 64, Hc / 64), blk, 0, stream>>>(l_h, Hc, W_a, Hc, l_q, Hc, b_a, Hc, 0);
        att_scores<<<dim3((Bc * Lc) / 4), blk, 0, stream>>>(l_q, Hc, l_keys, V_a, b_va, l_e);
        softmax_L<<<dim3(Bc), blk, 0, stream>>>(l_e);
        z_kernel<<<dim3(Bc, 2), blk, 0, stream>>>(l_e, feats, l_z);
        gemm_f32<<<dim3(Bc / 64, Ec / 64), blk, 0, stream>>>(l_h, Hc, W_beta, Ec, l_sb, Ec, b_beta, Hc, 0);
        ctx_build<<<dim3(Bc, 4), blk, 0, stream>>>(l_z, l_sb, caption, emb, l_ctx, t);
        gemm_f32<<<dim3(Bc / 64, (4 * Hc) / 64), blk, 0, stream>>>(l_ctx, 2 * Ec, W_lstm, 4 * Hc, l_gates, 4 * Hc, b_lstm, 2 * Ec, 0);
        gemm_f32<<<dim3(Bc / 64, (4 * Hc) / 64), blk, 0, stream>>>(l_h, Hc, U_lstm, 4 * Hc, l_gates, 4 * Hc, nullptr, Hc, 1);
        lstm_elem<<<dim3((Bc * Hc) / 256), blk, 0, stream>>>(l_gates, l_h, l_c, Hc);
        gemm_f32<<<dim3(Bc / 64, Vc / 64), blk, 0, stream>>>(l_h, Hc, W_out, Vc, out + (size_t)t * Vc, Tc * Vc, b_out, Hc, 0);
        softmax_V<<<dim3(Bc), blk, 0, stream>>>(out, t);
    }
}